// Round 3
// baseline (104.310 us; speedup 1.0000x reference)
//
#include <hip/hip_runtime.h>
#include <hip/hip_bf16.h>

typedef __attribute__((ext_vector_type(8))) short short8;
typedef __attribute__((ext_vector_type(4))) float floatx4;

#define NROWS 4096
#define NHALF 2048
#define DDIM  128
#define LDST  136                 // LDS row stride in ushorts (272B, 2-way conflict = free)
#define SQRT_SCALE 2.6857914f     // sqrt(1/(0.2*ln2)); dot of stored z == (sim/T)*log2(e)
#define LN2 0.69314718056f

// ws float layout: [0]=loss acc, [1]=all_num,
// rowsum [64, +16384), diag [16448, +16384), pos [32832, +16384)
#define WS_ROWSUM_OFF 64
#define WS_DIAG_OFF   16448
#define WS_POS_OFF    32832
#define WS_Z_BYTE_OFF 196864      // (64+3*16384)*4, 16B aligned

__device__ inline unsigned short f2bf(float f) {
    unsigned u = __builtin_bit_cast(unsigned, f);
    u += 0x7fffu + ((u >> 16) & 1u);          // RNE
    return (unsigned short)(u >> 16);
}

// ---------------- kernel 1: normalize + scale + cast to bf16; zero acc; all_num ------------
// 2049 blocks: 2048 x 8 rows (float4/lane, 32 lanes per row), block 2048 does jv sum.
__global__ __launch_bounds__(256) void k_norm(const float* __restrict__ emb_i,
                                              const float* __restrict__ emb_j,
                                              const float* __restrict__ jv,
                                              float* __restrict__ wsf,
                                              unsigned short* __restrict__ z) {
    int bx = blockIdx.x, tid = threadIdx.x;
    if (bx == 2048) {                         // all_num = sum(joint_valid)
        __shared__ float sred[256];
        float s = 0.f;
        #pragma unroll
        for (int i = 0; i < 8; ++i) s += jv[tid + 256 * i];
        sred[tid] = s; __syncthreads();
        for (int off = 128; off > 0; off >>= 1) {
            if (tid < off) sred[tid] += sred[tid + off];
            __syncthreads();
        }
        if (tid == 0) wsf[1] = sred[0];
        return;
    }
    int gid = bx * 256 + tid;                 // zero loss acc + rowsum (ws poisoned each call)
    if (gid == 0) wsf[0] = 0.f;
    if (gid >= WS_ROWSUM_OFF && gid < WS_ROWSUM_OFF + 16384) wsf[gid] = 0.f;

    int wave = tid >> 6, lane = tid & 63, half = lane >> 5, sl = lane & 31;
    int r = bx * 8 + wave * 2 + half;         // global row 0..16383
    int l = r >> 12, n = r & 4095;
    const float* src = (n < NHALF) ? (emb_i + ((size_t)l * NHALF + n) * DDIM)
                                   : (emb_j + ((size_t)l * NHALF + (n - NHALF)) * DDIM);
    float4 v = *(const float4*)(src + sl * 4);
    float ss = v.x * v.x + v.y * v.y + v.z * v.z + v.w * v.w;
    #pragma unroll
    for (int off = 1; off < 32; off <<= 1) ss += __shfl_xor(ss, off);  // within 32-lane half
    float inv = SQRT_SCALE / fmaxf(sqrtf(ss), 1e-12f);
    unsigned p0 = ((unsigned)f2bf(v.y * inv) << 16) | (unsigned)f2bf(v.x * inv);
    unsigned p1 = ((unsigned)f2bf(v.w * inv) << 16) | (unsigned)f2bf(v.z * inv);
    *(uint2*)(z + (size_t)r * DDIM + sl * 4) = (uint2){p0, p1};
}

// ---------------- kernel 2: symmetric fused sim GEMM + rowwise exp2-sum + diag/pos ---------
// Upper-triangular 256x256 tiles only: 136 tiles/l x 4 = 544 blocks. Off-diagonal tiles
// credit exp values to BOTH row-sums (rows R) and col-sums (rows C) — sim is symmetric.
// 4 waves, 64 rows/wave, A-frags resident in VGPRs; 128-col LDS stages (2 per block).
__global__ __launch_bounds__(256) void k_sim(const unsigned short* __restrict__ z,
                                             float* __restrict__ rowsum,
                                             float* __restrict__ diag,
                                             float* __restrict__ pos) {
    __shared__ __align__(16) unsigned short lds[128 * LDST];
    __shared__ float colsum[256];
    int bx = blockIdx.x, tid = threadIdx.x;
    int l = bx & 3, t = bx >> 2;              // t in [0,136): upper-tri tile index
    int rb = 0;
    while (t >= 16 - rb) { t -= 16 - rb; ++rb; }
    int cb = rb + t;
    bool offdiag = (cb != rb);
    bool isposT  = (cb == (rb ^ 8));          // tile holding the positive pairs
    int R = rb * 256, C = cb * 256;
    int wave = tid >> 6, lane = tid & 63, m = lane & 15, quad = lane >> 4;
    const unsigned short* zl = z + (size_t)l * NROWS * DDIM;
    int l4 = l * NROWS;
    int wr0 = R + wave * 64;

    colsum[tid] = 0.f;                        // synced by first __syncthreads below

    short8 a[4][4];                           // 4 row-subtiles x 4 k-steps, resident
    #pragma unroll
    for (int rs = 0; rs < 4; ++rs) {
        const unsigned short* p = zl + (size_t)(wr0 + rs * 16 + m) * DDIM + quad * 8;
        #pragma unroll
        for (int kk = 0; kk < 4; ++kk) a[rs][kk] = *(const short8*)(p + kk * 32);
    }
    floatx4 rsum[4];
    #pragma unroll
    for (int rs = 0; rs < 4; ++rs) rsum[rs] = (floatx4){0.f, 0.f, 0.f, 0.f};

    for (int stg = 0; stg < 2; ++stg) {       // 2 x 128-col LDS stages
        int cg0 = C + stg * 128;
        __syncthreads();
        #pragma unroll
        for (int i = 0; i < 8; ++i) {         // stage 128x128 bf16 (32KB), 16B chunks
            int chunk = tid + 256 * i;
            int col = chunk >> 4, off = chunk & 15;
            uint4 d = *(const uint4*)(zl + (size_t)(cg0 + col) * DDIM + off * 8);
            *(uint4*)&lds[col * LDST + off * 8] = d;
        }
        __syncthreads();
        #pragma unroll
        for (int cs = 0; cs < 8; ++cs) {      // 16-col subtiles
            int lc = stg * 128 + cs * 16;     // local col base within tile
            const unsigned short* lp = &lds[(cs * 16 + m) * LDST + quad * 8];
            short8 b0 = *(const short8*)(lp);
            short8 b1 = *(const short8*)(lp + 32);
            short8 b2 = *(const short8*)(lp + 64);
            short8 b3 = *(const short8*)(lp + 96);
            float cacc = 0.f;
            #pragma unroll
            for (int rs = 0; rs < 4; ++rs) {
                floatx4 acc = (floatx4){0.f, 0.f, 0.f, 0.f};
                acc = __builtin_amdgcn_mfma_f32_16x16x32_bf16(a[rs][0], b0, acc, 0, 0, 0);
                acc = __builtin_amdgcn_mfma_f32_16x16x32_bf16(a[rs][1], b1, acc, 0, 0, 0);
                acc = __builtin_amdgcn_mfma_f32_16x16x32_bf16(a[rs][2], b2, acc, 0, 0, 0);
                acc = __builtin_amdgcn_mfma_f32_16x16x32_bf16(a[rs][3], b3, acc, 0, 0, 0);
                int lr = wave * 64 + rs * 16; // local row base
                if (lr == lc) {               // tile-diagonal 16x16 subtile (wave-uniform)
                    int c = m - (quad << 2);  // lane holds (row=lr+m) iff quad*4+c == m
                    if (c >= 0 && c < 4) {
                        float v = acc[c];
                        if (!offdiag) diag[l4 + R + lr + m] = v;
                        else if (isposT) {    // sim(r, r^2048): pos for BOTH partner rows
                            pos[l4 + R + lr + m] = v;
                            pos[l4 + C + lr + m] = v;
                        }
                    }
                }
                float e0 = __builtin_amdgcn_exp2f(acc[0]);
                float e1 = __builtin_amdgcn_exp2f(acc[1]);
                float e2 = __builtin_amdgcn_exp2f(acc[2]);
                float e3 = __builtin_amdgcn_exp2f(acc[3]);
                rsum[rs][0] += e0; rsum[rs][1] += e1;
                rsum[rs][2] += e2; rsum[rs][3] += e3;
                cacc += (e0 + e1) + (e2 + e3);
            }
            if (offdiag) {                    // col partial: sum over rows for col lc+m
                cacc += __shfl_xor(cacc, 16);
                cacc += __shfl_xor(cacc, 32);
                if (quad == 0) atomicAdd(&colsum[lc + m], cacc);
            }
        }
    }
    // row-sums: reduce across the 16 column-lanes (bits 0..3)
    #pragma unroll
    for (int off = 1; off < 16; off <<= 1)
        #pragma unroll
        for (int rs = 0; rs < 4; ++rs)
            #pragma unroll
            for (int c = 0; c < 4; ++c)
                rsum[rs][c] += __shfl_xor(rsum[rs][c], off);
    if (m == 0) {
        #pragma unroll
        for (int rs = 0; rs < 4; ++rs)
            #pragma unroll
            for (int c = 0; c < 4; ++c) {
                int rg = wr0 + rs * 16 + quad * 4 + c;
                atomicAdd(&rowsum[l4 + rg], rsum[rs][c]);
            }
    }
    if (offdiag) {                            // flush col-sums to the mirror rows
        __syncthreads();
        atomicAdd(&rowsum[l4 + C + tid], colsum[tid]);
    }
}

// ---------------- kernel 3: per-row loss from rowsum/diag/pos, 1 atomic per block ----------
__global__ __launch_bounds__(256) void k_loss(const float* __restrict__ jv,
                                              const float* __restrict__ rowsum,
                                              const float* __restrict__ diag,
                                              const float* __restrict__ pos,
                                              float* __restrict__ wsf) {
    __shared__ float sred[256];
    int tid = threadIdx.x;
    int r = blockIdx.x * 256 + tid;           // 64 blocks x 256 = 16384 rows
    int n = r & 4095;
    float denom = rowsum[r] - __builtin_amdgcn_exp2f(diag[r]);  // exact cancel vs rowsum term
    float contrib = LN2 * (__builtin_amdgcn_logf(denom) - pos[r]);
    float local = contrib * jv[n & (NHALF - 1)];
    sred[tid] = local; __syncthreads();
    for (int off = 128; off > 0; off >>= 1) {
        if (tid < off) sred[tid] += sred[tid + off];
        __syncthreads();
    }
    if (tid == 0) atomicAdd(&wsf[0], sred[0]);
}

// ---------------- kernel 4: final scalar ---------------------------------------------------
__global__ void k_final(const float* __restrict__ wsf, float* __restrict__ out) {
    if (threadIdx.x == 0) out[0] = wsf[0] / (2.f * wsf[1]);
}

extern "C" void kernel_launch(void* const* d_in, const int* in_sizes, int n_in,
                              void* d_out, int out_size, void* d_ws, size_t ws_size,
                              hipStream_t stream) {
    const float* emb_i = (const float*)d_in[0];
    const float* emb_j = (const float*)d_in[1];
    const float* jv    = (const float*)d_in[2];
    float* wsf    = (float*)d_ws;
    float* rowsum = wsf + WS_ROWSUM_OFF;
    float* diag   = wsf + WS_DIAG_OFF;
    float* pos    = wsf + WS_POS_OFF;
    unsigned short* z = (unsigned short*)((char*)d_ws + WS_Z_BYTE_OFF);
    float* out = (float*)d_out;

    k_norm <<<2049, 256, 0, stream>>>(emb_i, emb_j, jv, wsf, z);
    k_sim  <<<544,  256, 0, stream>>>(z, rowsum, diag, pos);
    k_loss <<<64,   256, 0, stream>>>(jv, rowsum, diag, pos, wsf);
    k_final<<<1,    64,  0, stream>>>(wsf, out);
}

// Round 4
// 102.636 us; speedup vs baseline: 1.0163x; 1.0163x over previous
//
#include <hip/hip_runtime.h>
#include <hip/hip_bf16.h>

typedef __attribute__((ext_vector_type(8))) short short8;
typedef __attribute__((ext_vector_type(4))) float floatx4;

#define NROWS 4096
#define NHALF 2048
#define DDIM  128
#define SQRT_SCALE 2.6857914f     // sqrt(1/(0.2*ln2)); dot of stored z == (sim/T)*log2(e)
#define LN2 0.69314718056f

// ws float layout: [0]=loss acc, [1]=all_num,
// rowpart [64, +8*16384), diag [131136, +16384), pos [147520, +16384), z after.
#define WS_ROWPART_OFF 64
#define WS_DIAG_OFF   131136
#define WS_POS_OFF    147520
#define WS_Z_BYTE_OFF 655616      // (147520+16384)*4, 16B aligned

__device__ inline unsigned short f2bf(float f) {
    unsigned u = __builtin_bit_cast(unsigned, f);
    u += 0x7fffu + ((u >> 16) & 1u);          // RNE
    return (unsigned short)(u >> 16);
}

// ---------------- kernel 1: normalize + scale + cast to bf16; all_num ----------------------
// 2049 blocks: 2048 x 8 rows (float4/lane, 32 lanes per row), block 2048 does jv sum.
__global__ __launch_bounds__(256) void k_norm(const float* __restrict__ emb_i,
                                              const float* __restrict__ emb_j,
                                              const float* __restrict__ jv,
                                              float* __restrict__ wsf,
                                              unsigned short* __restrict__ z) {
    int bx = blockIdx.x, tid = threadIdx.x;
    if (bx == 2048) {                         // all_num = sum(joint_valid)
        __shared__ float sred[256];
        float s = 0.f;
        #pragma unroll
        for (int i = 0; i < 8; ++i) s += jv[tid + 256 * i];
        sred[tid] = s; __syncthreads();
        for (int off = 128; off > 0; off >>= 1) {
            if (tid < off) sred[tid] += sred[tid + off];
            __syncthreads();
        }
        if (tid == 0) wsf[1] = sred[0];
        return;
    }
    if (bx == 0 && tid == 0) wsf[0] = 0.f;    // zero loss accumulator (ws poisoned each call)

    int wave = tid >> 6, lane = tid & 63, half = lane >> 5, sl = lane & 31;
    int r = bx * 8 + wave * 2 + half;         // global row 0..16383
    int l = r >> 12, n = r & 4095;
    const float* src = (n < NHALF) ? (emb_i + ((size_t)l * NHALF + n) * DDIM)
                                   : (emb_j + ((size_t)l * NHALF + (n - NHALF)) * DDIM);
    float4 v = *(const float4*)(src + sl * 4);
    float ss = v.x * v.x + v.y * v.y + v.z * v.z + v.w * v.w;
    #pragma unroll
    for (int off = 1; off < 32; off <<= 1) ss += __shfl_xor(ss, off);  // within 32-lane half
    float inv = SQRT_SCALE / fmaxf(sqrtf(ss), 1e-12f);
    unsigned p0 = ((unsigned)f2bf(v.y * inv) << 16) | (unsigned)f2bf(v.x * inv);
    unsigned p1 = ((unsigned)f2bf(v.w * inv) << 16) | (unsigned)f2bf(v.z * inv);
    *(uint2*)(z + (size_t)r * DDIM + sl * 4) = (uint2){p0, p1};
}

// ---------------- kernel 2: LDS-free streaming sim + rowwise exp2-sum + diag/pos -----------
// grid 512: l(4) x rowband(16, 256 rows) x colgroup(8, 512 cols). 4 waves x 64 rows.
// No LDS, no barriers, no atomics. A-frags resident; B-frags double-buffered from global
// (L2/L1-resident; the 4 waves of a block share the same B stream -> L1 broadcast).
// Partial row sums -> plain stores to rowpart[cg][16384]; k_loss sums the 8 parts.
__global__ __launch_bounds__(256) void k_sim(const unsigned short* __restrict__ z,
                                             float* __restrict__ rowpart,
                                             float* __restrict__ diag,
                                             float* __restrict__ pos) {
    int bx = blockIdx.x, tid = threadIdx.x;
    int l = bx & 3, rb = (bx >> 2) & 15, cg = bx >> 6;
    int wave = tid >> 6, lane = tid & 63, m = lane & 15, quad = lane >> 4;
    const unsigned short* zl = z + (size_t)l * NROWS * DDIM;
    int l4 = l * NROWS;
    int R0 = rb * 256 + wave * 64;            // wave's row base (local to l)
    int C0 = cg * 512;                        // block's col base

    short8 a[4][4];                           // 4 row-subtiles x 4 k-steps, resident (64 VGPR)
    #pragma unroll
    for (int rs = 0; rs < 4; ++rs) {
        const unsigned short* p = zl + (size_t)(R0 + rs * 16 + m) * DDIM + quad * 8;
        #pragma unroll
        for (int kk = 0; kk < 4; ++kk) a[rs][kk] = *(const short8*)(p + kk * 32);
    }
    floatx4 rsum[4];
    #pragma unroll
    for (int rs = 0; rs < 4; ++rs) rsum[rs] = (floatx4){0.f, 0.f, 0.f, 0.f};

    const unsigned short* bp = zl + (size_t)(C0 + m) * DDIM + quad * 8;
    short8 bc[4], bn[4];
    #pragma unroll
    for (int k = 0; k < 4; ++k) bc[k] = *(const short8*)(bp + k * 32);

    #pragma unroll 2
    for (int cs = 0; cs < 32; ++cs) {         // 16-col steps across the 512-col group
        if (cs < 31) {                        // prefetch next B-frag set
            const unsigned short* q = bp + (size_t)(cs + 1) * 16 * DDIM;
            #pragma unroll
            for (int k = 0; k < 4; ++k) bn[k] = *(const short8*)(q + k * 32);
        }
        int c0 = C0 + cs * 16;                // tile col base (wave-uniform)
        #pragma unroll
        for (int rs = 0; rs < 4; ++rs) {
            floatx4 acc = (floatx4){0.f, 0.f, 0.f, 0.f};
            acc = __builtin_amdgcn_mfma_f32_16x16x32_bf16(a[rs][0], bc[0], acc, 0, 0, 0);
            acc = __builtin_amdgcn_mfma_f32_16x16x32_bf16(a[rs][1], bc[1], acc, 0, 0, 0);
            acc = __builtin_amdgcn_mfma_f32_16x16x32_bf16(a[rs][2], bc[2], acc, 0, 0, 0);
            acc = __builtin_amdgcn_mfma_f32_16x16x32_bf16(a[rs][3], bc[3], acc, 0, 0, 0);
            int rbase = R0 + rs * 16;
            if (c0 == rbase || c0 == (rbase ^ 2048)) {   // rare, wave-uniform
                int c = m - (quad << 2);      // lane holds (row=rbase+m) iff quad*4+c == m
                if (c >= 0 && c < 4)
                    ((c0 == rbase) ? diag : pos)[l4 + rbase + m] = acc[c];
            }
            rsum[rs][0] += __builtin_amdgcn_exp2f(acc[0]);
            rsum[rs][1] += __builtin_amdgcn_exp2f(acc[1]);
            rsum[rs][2] += __builtin_amdgcn_exp2f(acc[2]);
            rsum[rs][3] += __builtin_amdgcn_exp2f(acc[3]);
        }
        if (cs < 31) {
            #pragma unroll
            for (int k = 0; k < 4; ++k) bc[k] = bn[k];
        }
    }
    // reduce across the 16 column-lanes (bits 0..3 of lane)
    #pragma unroll
    for (int off = 1; off < 16; off <<= 1)
        #pragma unroll
        for (int rs = 0; rs < 4; ++rs)
            #pragma unroll
            for (int c = 0; c < 4; ++c)
                rsum[rs][c] += __shfl_xor(rsum[rs][c], off);
    if (m == 0) {                             // plain stores: unique (cg,row) per value
        #pragma unroll
        for (int rs = 0; rs < 4; ++rs)
            #pragma unroll
            for (int c = 0; c < 4; ++c) {
                int rg = R0 + rs * 16 + quad * 4 + c;
                rowpart[cg * 16384 + l4 + rg] = rsum[rs][c];
            }
    }
}

// ---------------- kernel 3: per-row loss from rowpart/diag/pos, 1 atomic per block ---------
__global__ __launch_bounds__(256) void k_loss(const float* __restrict__ jv,
                                              const float* __restrict__ rowpart,
                                              const float* __restrict__ diag,
                                              const float* __restrict__ pos,
                                              float* __restrict__ wsf) {
    __shared__ float sred[256];
    int tid = threadIdx.x;
    int r = blockIdx.x * 256 + tid;           // 64 blocks x 256 = 16384 rows
    int n = r & 4095;
    float tot = 0.f;
    #pragma unroll
    for (int g = 0; g < 8; ++g) tot += rowpart[g * 16384 + r];
    float denom = tot - __builtin_amdgcn_exp2f(diag[r]);   // exact cancel of diagonal term
    float contrib = LN2 * (__builtin_amdgcn_logf(denom) - pos[r]);
    float local = contrib * jv[n & (NHALF - 1)];
    sred[tid] = local; __syncthreads();
    for (int off = 128; off > 0; off >>= 1) {
        if (tid < off) sred[tid] += sred[tid + off];
        __syncthreads();
    }
    if (tid == 0) atomicAdd(&wsf[0], sred[0]);
}

// ---------------- kernel 4: final scalar ---------------------------------------------------
__global__ void k_final(const float* __restrict__ wsf, float* __restrict__ out) {
    if (threadIdx.x == 0) out[0] = wsf[0] / (2.f * wsf[1]);
}

extern "C" void kernel_launch(void* const* d_in, const int* in_sizes, int n_in,
                              void* d_out, int out_size, void* d_ws, size_t ws_size,
                              hipStream_t stream) {
    const float* emb_i = (const float*)d_in[0];
    const float* emb_j = (const float*)d_in[1];
    const float* jv    = (const float*)d_in[2];
    float* wsf     = (float*)d_ws;
    float* rowpart = wsf + WS_ROWPART_OFF;
    float* diag    = wsf + WS_DIAG_OFF;
    float* pos     = wsf + WS_POS_OFF;
    unsigned short* z = (unsigned short*)((char*)d_ws + WS_Z_BYTE_OFF);
    float* out = (float*)d_out;

    k_norm <<<2049, 256, 0, stream>>>(emb_i, emb_j, jv, wsf, z);
    k_sim  <<<512,  256, 0, stream>>>(z, rowpart, diag, pos);
    k_loss <<<64,   256, 0, stream>>>(jv, rowpart, diag, pos, wsf);
    k_final<<<1,    64,  0, stream>>>(wsf, out);
}